// Round 10
// baseline (4242.003 us; speedup 1.0000x reference)
//
#include <hip/hip_runtime.h>
#include <hip/hip_bf16.h>

// LSTM: B=16384, T=5, IN=11, H=512. Output = final cell state c [B,H] fp32.
//
// R20 = exact R14 (measured best, 127us dispatch; 5 spill-fix attempts all
// failed or regressed -> spill is allocator-structural, stop fighting it)
// + two zero-register phase-overlap changes:
//  1. ji-STAGGER: even waves do ji {0,1}, odd waves {1,0}. Phases decorrelate
//     -> at any instant ~half the SIMD's waves are in the MFMA K-loop while
//     the rest run the VALU epilogue; pipes overlap (m114). Per-ji math
//     order unchanged -> bit-identical output (absmax 0.004394531).
//  2. s_setprio(1) around the K-loop MFMA cluster (T5): pays exactly when
//     waves have role diversity, which the stagger creates.
// Evidence: at 127us, L2 B-BW ~11 TB/s << 34.5 ceiling, MfmaUtil 24 +
// VALUBusy 39 = 63% with lock-step phases -> overlap is the remaining lever.

#define HID   512
#define ROWS  64
#define NTHR  1024                  // 16 waves
// h-buffer: i8 region 32 KB (8 ks x 4 rt x 1KB) + f16 x/bias frag 4 KB
#define HBBYTES 36864
#define HB    (HBBYTES / 2)         // halves per buffer = 18432
#define SMEM_HALFS (2 * HB + 64 * 56 + 1024)   // + xlds + pad (anti 2-block/CU)
#define SMEM_BYTES (SMEM_HALFS * 2)            // 82944 B -> 1 block/CU

// Wt workspace layout (bytes):
#define WT_I8   0                   // 32 j x 8 ks x 4 g x 1024 B = 1 MB
#define WT_F16X 1048576             // 32 j x 4 g x 1024 B = 128 KB
#define WT_CSC  1179648             // 2048 f32 col scales (8 KB)

#define L2E   1.442695041f
#define L2E2  2.885390082f

typedef _Float16 f16x8 __attribute__((ext_vector_type(8)));
typedef float f32x4 __attribute__((ext_vector_type(4)));
typedef int v4i __attribute__((ext_vector_type(4)));

// ---------------- prologue: pack W (verbatim from R14, passed) --------------
__global__ __launch_bounds__(256) void pack_w(const float* __restrict__ Wih,
                                              const float* __restrict__ Whh,
                                              const float* __restrict__ bih,
                                              const float* __restrict__ bhh,
                                              char* __restrict__ Wt) {
    const int col  = blockIdx.x * 4 + (threadIdx.x >> 6);   // 0..2047
    const int lane = threadIdx.x & 63;
    const int g = col >> 9;
    const int j = (col & 511) >> 4;
    const int c = col & 15;

    // coalesced 2 KB row read: k = lane*8 .. +7
    const float4* __restrict__ src = (const float4*)(Whh + (size_t)col * 512);
    float4 u0 = src[lane * 2 + 0];
    float4 u1 = src[lane * 2 + 1];
    float w[8] = {u0.x, u0.y, u0.z, u0.w, u1.x, u1.y, u1.z, u1.w};

    // wave-reduce max |w| over the 512 column entries
    float m = 0.0f;
#pragma unroll
    for (int q = 0; q < 8; q++) m = fmaxf(m, fabsf(w[q]));
#pragma unroll
    for (int off = 32; off >= 1; off >>= 1)
        m = fmaxf(m, __shfl_xor(m, off));
    m = fmaxf(m, 1e-12f);
    const float inv = 127.0f / m;

    // quantize and pack 8 bytes
    unsigned lo = 0, hi = 0;
#pragma unroll
    for (int q = 0; q < 4; q++)
        lo |= ((unsigned)((int)rintf(w[q] * inv) & 0xff)) << (8 * q);
#pragma unroll
    for (int q = 0; q < 4; q++)
        hi |= ((unsigned)((int)rintf(w[4 + q] * inv) & 0xff)) << (8 * q);

    const int ks8 = lane >> 3;          // k>>6
    const int p   = (lane >> 1) & 3;    // (k&63)>>4
    const int bo  = (lane & 1) * 8;     // byte offset within 16
    size_t addr = ((size_t)(j * 8 + ks8) * 4 + g) * 1024 + (c + 16 * p) * 16 + bo;
    uint2 pk = {lo, hi};
    *(uint2*)(Wt + WT_I8 + addr) = pk;

    // combined dequant scale: (m/127) * (1/127) * gate-log2e factor
    if (lane == 0) {
        float* csc = (float*)(Wt + WT_CSC);
        csc[col] = (m / 16129.0f) * ((g == 2) ? L2E2 : L2E);
    }

    // f16 x/bias frag (k' = 0..31: x 0..10, bias 11, pad), lanes 0..3 = chunk
    if (lane < 4) {
        const float scale = (g == 2) ? L2E2 : L2E;
        _Float16 t[8];
        const int kb = lane * 8;
#pragma unroll
        for (int q = 0; q < 8; q++) {
            int k = kb + q;
            float x;
            if (k < 11)       x = Wih[col * 11 + k];
            else if (k == 11) x = bih[col] + bhh[col];
            else              x = 0.0f;
            t[q] = (_Float16)(x * scale);
        }
        *(f16x8*)(Wt + WT_F16X + ((size_t)j * 4 + g) * 1024
                  + (c + 16 * lane) * 16) = *(const f16x8*)t;
    }
}

// ---------------- one recurrent step ----------------------------------------
// Wave w: rows rt 0..3 (64 rows), col-quads j = 2w+ji, all 4 gates.
// STAGGER: even waves process ji {0,1}, odd waves {1,0} -> phase overlap.
// i8 h region: unit (ks*4+rt)*1024, lane L: 16 bytes, row rt*16+(L&15),
//   k = ks*64 + (L>>4)*16 + b.  f16 x region at byte 32768, unit rt*1024.
template <bool FIRST, bool WRITE_H>
__device__ __forceinline__ void run_step(const char* __restrict__ cur,
                                         char* __restrict__ nxt,
                                         const char* __restrict__ wbase, // uniform
                                         const float (&sc)[2][4],
                                         f32x4* __restrict__ cacc,
                                         const int wave, const int lane) {
    const int c  = lane & 15;
    const int kq = lane >> 4;
    const int lane16 = lane * 16;
#pragma unroll
    for (int jip = 0; jip < 2; jip++) {
        const int ji = jip ^ (wave & 1);      // wave-uniform stagger
        const int j  = wave * 2 + ji;
        const int jj = __builtin_amdgcn_readfirstlane(j);   // SGPR

        v4i acc[4][4];                        // [row-tile][gate]
        if (!FIRST) {
#pragma unroll
            for (int rt = 0; rt < 4; rt++)
#pragma unroll
                for (int g = 0; g < 4; g++) {
                    v4i z = {0, 0, 0, 0};
                    acc[rt][g] = z;
                }
            const char* __restrict__ w0 = wbase + (size_t)jj * 32768; // SGPR base
            const char* __restrict__ ac = cur + lane16;
#pragma unroll 1                              // REAL loop (anti-spill)
            for (int ks = 0; ks < 8; ks++) {
                v4i B0 = *(const v4i*)(w0 + lane16 + 0);
                v4i B1 = *(const v4i*)(w0 + lane16 + 1024);
                v4i B2 = *(const v4i*)(w0 + lane16 + 2048);
                v4i B3 = *(const v4i*)(w0 + lane16 + 3072);
                __builtin_amdgcn_s_setprio(1);    // T5: MFMA cluster priority
#pragma unroll
                for (int rt = 0; rt < 4; rt++) {
                    v4i A = *(const v4i*)(ac + rt * 1024);
                    acc[rt][0] = __builtin_amdgcn_mfma_i32_16x16x64_i8(A, B0, acc[rt][0], 0, 0, 0);
                    acc[rt][1] = __builtin_amdgcn_mfma_i32_16x16x64_i8(A, B1, acc[rt][1], 0, 0, 0);
                    acc[rt][2] = __builtin_amdgcn_mfma_i32_16x16x64_i8(A, B2, acc[rt][2], 0, 0, 0);
                    acc[rt][3] = __builtin_amdgcn_mfma_i32_16x16x64_i8(A, B3, acc[rt][3], 0, 0, 0);
                }
                __builtin_amdgcn_s_setprio(0);
                w0 += 4096;                   // s_add (uniform)
                ac += 4096;                   // v_add (LDS addr)
            }
        }

        // dequant: per-column combined scale (log2e folded)
        f32x4 af[4][4];                       // [row-tile][gate] f32
        if (!FIRST) {
#pragma unroll
            for (int rt = 0; rt < 4; rt++)
#pragma unroll
                for (int r = 0; r < 4; r++) {
                    af[rt][0][r] = (float)acc[rt][0][r] * sc[ji][0];
                    af[rt][1][r] = (float)acc[rt][1][r] * sc[ji][1];
                    af[rt][2][r] = (float)acc[rt][2][r] * sc[ji][2];
                    af[rt][3][r] = (float)acc[rt][3][r] * sc[ji][3];
                }
        } else {
#pragma unroll
            for (int rt = 0; rt < 4; rt++)
#pragma unroll
                for (int g = 0; g < 4; g++) {
                    f32x4 z = {0.f, 0.f, 0.f, 0.f};
                    af[rt][g] = z;
                }
        }

        // f16 x/bias slice (pre-scaled by log2e / 2log2e)
        {
            const char* __restrict__ wx = wbase + WT_F16X + (size_t)jj * 4096;
            f16x8 X0 = *(const f16x8*)(wx + lane16 + 0);
            f16x8 X1 = *(const f16x8*)(wx + lane16 + 1024);
            f16x8 X2 = *(const f16x8*)(wx + lane16 + 2048);
            f16x8 X3 = *(const f16x8*)(wx + lane16 + 3072);
            const char* __restrict__ ax = cur + 32768 + lane16;
#pragma unroll
            for (int rt = 0; rt < 4; rt++) {
                f16x8 A = *(const f16x8*)(ax + rt * 1024);
                af[rt][0] = __builtin_amdgcn_mfma_f32_16x16x32_f16(A, X0, af[rt][0], 0, 0, 0);
                af[rt][1] = __builtin_amdgcn_mfma_f32_16x16x32_f16(A, X1, af[rt][1], 0, 0, 0);
                af[rt][2] = __builtin_amdgcn_mfma_f32_16x16x32_f16(A, X2, af[rt][2], 0, 0, 0);
                af[rt][3] = __builtin_amdgcn_mfma_f32_16x16x32_f16(A, X3, af[rt][3], 0, 0, 0);
            }
        }

        // epilogue: gates exp2-ready. C/D: col = lane&15, row = kq*4 + r.
#pragma unroll
        for (int rt = 0; rt < 4; rt++) {
            f32x4 cv = cacc[ji * 4 + rt];
#pragma unroll
            for (int r = 0; r < 4; r++) {
                float ai  = af[rt][0][r];         // i * log2e
                float afv = af[rt][1][r];         // f * log2e
                float ag  = af[rt][2][r];         // 2g * log2e
                float ao  = af[rt][3][r];         // o * log2e
                float ei = __builtin_amdgcn_exp2f(-ai);
                float eg = __builtin_amdgcn_exp2f(ag);
                // sig(i)*tanh(g) = (eg-1) / ((1+ei)*(1+eg))
                float ig = (eg - 1.0f) *
                           __builtin_amdgcn_rcpf((1.0f + ei) * (1.0f + eg));
                float ef = __builtin_amdgcn_exp2f(-afv);
                float cn = __builtin_amdgcn_rcpf(1.0f + ef) * cv[r] + ig;
                cv[r] = cn;
                if (WRITE_H) {
                    float eo = __builtin_amdgcn_exp2f(-ao);
                    float ec = __builtin_amdgcn_exp2f(cn * L2E2);
                    float hn = (ec - 1.0f) *
                               __builtin_amdgcn_rcpf((1.0f + eo) * (1.0f + ec));
                    // h -> i8 into next buffer's A-frag layout
                    int q = (int)rintf(hn * 127.0f);
                    nxt[(((j >> 2) * 4 + rt) * 64 + (kq * 4 + r) + 16 * (j & 3)) * 16 + c]
                        = (char)q;
                }
            }
            cacc[ji * 4 + rt] = cv;
        }
    }
}

// x_t (11 elems) into the f16 x-frag region of a buffer.
__device__ __forceinline__ void xfill(_Float16* __restrict__ nxt,
                                      const _Float16* __restrict__ xlds,
                                      int step, int tid) {
    for (int i = tid; i < 64 * 11; i += NTHR) {
        int row = i / 11, xi = i - row * 11;
        int idx = ((32 + (row >> 4)) * 64 + ((row & 15) + 16 * (xi >> 3))) * 8
                  + (xi & 7);
        nxt[idx] = xlds[row * 56 + step * 11 + xi];
    }
}

// ---------------- main persistent kernel ------------------------------------
__global__ __launch_bounds__(NTHR, 4)
void lstm_main(const float* __restrict__ ts,
               const char* __restrict__ Wt,
               float* __restrict__ out) {
    extern __shared__ _Float16 smem[];
    _Float16* buf0h = smem;            // h buffers (i8 region + f16 x frag)
    _Float16* buf1h = smem + HB;
    _Float16* xlds  = smem + 2 * HB;   // [64][56] fp16 staged ts rows
    char* buf0 = (char*)buf0h;
    char* buf1 = (char*)buf1h;
    const int tid  = threadIdx.x;
    const int lane = tid & 63;
    const int wave = tid >> 6;         // 0..15
    const int b0   = blockIdx.x * ROWS;
    const char* wbase = Wt;

    // per-lane dequant scales (col = g*512 + j*16 + c), loaded once
    float sc[2][4];
    {
        const float* csc = (const float*)(Wt + WT_CSC);
        const int c = lane & 15;
#pragma unroll
        for (int ji = 0; ji < 2; ji++)
#pragma unroll
            for (int g = 0; g < 4; g++)
                sc[ji][g] = csc[g * 512 + (wave * 2 + ji) * 16 + c];
    }

    // zero both h buffers (covers i8 h region + f16 pad columns)
    {
        f16x8 z = {(_Float16)0, (_Float16)0, (_Float16)0, (_Float16)0,
                   (_Float16)0, (_Float16)0, (_Float16)0, (_Float16)0};
        for (int i = tid * 8; i < 2 * HB; i += NTHR * 8)
            *(f16x8*)(smem + i) = z;
    }
    // stage this block's time_series rows (coalesced) as fp16
    for (int i = tid; i < 64 * 55; i += NTHR) {
        int row = i / 55, e = i - row * 55;
        xlds[row * 56 + e] = (_Float16)ts[(size_t)(b0 + row) * 55 + e];
    }
    __syncthreads();
    // bias column (k'=11 -> chunk 1, byte 3) = 1.0 in both buffers; x_0 -> buf0
    if (tid < 128) {
        int bsel = tid >> 6, row = tid & 63;
        int idx = ((32 + (row >> 4)) * 64 + ((row & 15) + 16)) * 8 + 3;
        (bsel ? buf1h : buf0h)[idx] = (_Float16)1.0f;
    }
    xfill(buf0h, xlds, 0, tid);
    __syncthreads();

    f32x4 cacc[8];
#pragma unroll
    for (int i = 0; i < 8; i++) {
        f32x4 z = {0.f, 0.f, 0.f, 0.f};
        cacc[i] = z;
    }

    // t = 0: h == 0, only the x/bias slice contributes
    run_step<true, true>(buf0, buf1, wbase, sc, cacc, wave, lane);
    xfill(buf1h, xlds, 1, tid);
    __syncthreads();

    for (int t = 1; t < 4; t++) {
        char* cur = (t & 1) ? buf1 : buf0;
        char* nxt = (t & 1) ? buf0 : buf1;
        run_step<false, true>(cur, nxt, wbase, sc, cacc, wave, lane);
        xfill((t & 1) ? (_Float16*)buf0 : (_Float16*)buf1, xlds, t + 1, tid);
        __syncthreads();
    }
    // t = 4: no h write needed
    run_step<false, false>(buf0, buf1, wbase, sc, cacc, wave, lane);

    // write final c
    const int c = lane & 15, kq = lane >> 4;
#pragma unroll
    for (int ji = 0; ji < 2; ji++) {
        const int j = wave * 2 + ji;
#pragma unroll
        for (int rt = 0; rt < 4; rt++) {
            f32x4 cv = cacc[ji * 4 + rt];
#pragma unroll
            for (int r = 0; r < 4; r++)
                out[(size_t)(b0 + rt * 16 + kq * 4 + r) * HID + j * 16 + c] = cv[r];
        }
    }
}

extern "C" void kernel_launch(void* const* d_in, const int* in_sizes, int n_in,
                              void* d_out, int out_size, void* d_ws, size_t ws_size,
                              hipStream_t stream) {
    const float* ts  = (const float*)d_in[0];
    const float* Wih = (const float*)d_in[1];
    const float* Whh = (const float*)d_in[2];
    const float* bih = (const float*)d_in[3];
    const float* bhh = (const float*)d_in[4];
    float* out       = (float*)d_out;
    char* Wt         = (char*)d_ws;     // 1.13 MB packed weights + scales

    (void)in_sizes; (void)n_in; (void)out_size; (void)ws_size;

    hipFuncSetAttribute(reinterpret_cast<const void*>(lstm_main),
                        hipFuncAttributeMaxDynamicSharedMemorySize, SMEM_BYTES);

    pack_w<<<512, 256, 0, stream>>>(Wih, Whh, bih, bhh, Wt);
    lstm_main<<<256, NTHR, SMEM_BYTES, stream>>>(ts, Wt, out);
}

// Round 11
// 185.569 us; speedup vs baseline: 22.8595x; 22.8595x over previous
//
#include <hip/hip_runtime.h>
#include <hip/hip_bf16.h>

// LSTM: B=16384, T=5, IN=11, H=512. Output = final cell state c [B,H] fp32.
//
// R21: R20's stagger theory, implemented rule-#20-clean. R20's 4242us was
// NOT the theory failing: `ji = jip ^ (wave&1)` made sc[ji]/cacc[ji*4+rt]
// runtime-indexed register arrays -> scratch (FETCH 5.57 GB, SGPR 112).
// Fix: per-ji body is run_pass<FIRST, JI, WRITE_H> (JI = template param,
// all indices static); order chosen by wave-uniform branch:
//   even waves: pass<0> then pass<1>;  odd waves: pass<1> then pass<0>.
// -> at any instant ~half the SIMD's waves run the MFMA K-loop while the
// other half run the VALU dequant/epilogue; separate pipes overlap (m114).
// + T5 setprio(1) around the MFMA cluster (stagger provides role diversity).
// Everything else is exact R14 (measured best, 127us dispatch): af
// materialized, scales from LDS, same accumulation order -> bit-identical
// output (absmax 0.004394531).

#define HID   512
#define ROWS  64
#define NTHR  1024                  // 16 waves
// h-buffer: i8 region 32 KB (8 ks x 4 rt x 1KB) + f16 x/bias frag 4 KB
#define HBBYTES 36864
#define HB    (HBBYTES / 2)         // halves per buffer = 18432
#define SMEM_HALFS (2 * HB + 64 * 56 + 4096)   // + xlds + colscale(2048 f32)
#define SMEM_BYTES (SMEM_HALFS * 2)            // 89088 B -> 1 block/CU

// Wt workspace layout (bytes):
#define WT_I8   0                   // 32 j x 8 ks x 4 g x 1024 B = 1 MB
#define WT_F16X 1048576             // 32 j x 4 g x 1024 B = 128 KB
#define WT_CSC  1179648             // 2048 f32 col scales (8 KB)

#define L2E   1.442695041f
#define L2E2  2.885390082f

typedef _Float16 f16x8 __attribute__((ext_vector_type(8)));
typedef float f32x4 __attribute__((ext_vector_type(4)));
typedef int v4i __attribute__((ext_vector_type(4)));

// ---------------- prologue: pack W (verbatim from R14, passed) --------------
__global__ __launch_bounds__(256) void pack_w(const float* __restrict__ Wih,
                                              const float* __restrict__ Whh,
                                              const float* __restrict__ bih,
                                              const float* __restrict__ bhh,
                                              char* __restrict__ Wt) {
    const int col  = blockIdx.x * 4 + (threadIdx.x >> 6);   // 0..2047
    const int lane = threadIdx.x & 63;
    const int g = col >> 9;
    const int j = (col & 511) >> 4;
    const int c = col & 15;

    // coalesced 2 KB row read: k = lane*8 .. +7
    const float4* __restrict__ src = (const float4*)(Whh + (size_t)col * 512);
    float4 u0 = src[lane * 2 + 0];
    float4 u1 = src[lane * 2 + 1];
    float w[8] = {u0.x, u0.y, u0.z, u0.w, u1.x, u1.y, u1.z, u1.w};

    // wave-reduce max |w| over the 512 column entries
    float m = 0.0f;
#pragma unroll
    for (int q = 0; q < 8; q++) m = fmaxf(m, fabsf(w[q]));
#pragma unroll
    for (int off = 32; off >= 1; off >>= 1)
        m = fmaxf(m, __shfl_xor(m, off));
    m = fmaxf(m, 1e-12f);
    const float inv = 127.0f / m;

    // quantize and pack 8 bytes
    unsigned lo = 0, hi = 0;
#pragma unroll
    for (int q = 0; q < 4; q++)
        lo |= ((unsigned)((int)rintf(w[q] * inv) & 0xff)) << (8 * q);
#pragma unroll
    for (int q = 0; q < 4; q++)
        hi |= ((unsigned)((int)rintf(w[4 + q] * inv) & 0xff)) << (8 * q);

    const int ks8 = lane >> 3;          // k>>6
    const int p   = (lane >> 1) & 3;    // (k&63)>>4
    const int bo  = (lane & 1) * 8;     // byte offset within 16
    size_t addr = ((size_t)(j * 8 + ks8) * 4 + g) * 1024 + (c + 16 * p) * 16 + bo;
    uint2 pk = {lo, hi};
    *(uint2*)(Wt + WT_I8 + addr) = pk;

    // combined dequant scale: (m/127) * (1/127) * gate-log2e factor
    if (lane == 0) {
        float* csc = (float*)(Wt + WT_CSC);
        csc[col] = (m / 16129.0f) * ((g == 2) ? L2E2 : L2E);
    }

    // f16 x/bias frag (k' = 0..31: x 0..10, bias 11, pad), lanes 0..3 = chunk
    if (lane < 4) {
        const float scale = (g == 2) ? L2E2 : L2E;
        _Float16 t[8];
        const int kb = lane * 8;
#pragma unroll
        for (int q = 0; q < 8; q++) {
            int k = kb + q;
            float x;
            if (k < 11)       x = Wih[col * 11 + k];
            else if (k == 11) x = bih[col] + bhh[col];
            else              x = 0.0f;
            t[q] = (_Float16)(x * scale);
        }
        *(f16x8*)(Wt + WT_F16X + ((size_t)j * 4 + g) * 1024
                  + (c + 16 * lane) * 16) = *(const f16x8*)t;
    }
}

// ---------------- one j-column pass of a recurrent step ---------------------
// Wave w, pass JI (compile-time): col-quad j = 2w+JI, rows rt 0..3, 4 gates.
// i8 h region: unit (ks*4+rt)*1024, lane L: 16 bytes, row rt*16+(L&15),
//   k = ks*64 + (L>>4)*16 + b.  f16 x region at byte 32768, unit rt*1024.
// All sc/cacc indices static (rule #20). Body identical to R14's ji-loop.
template <bool FIRST, int JI, bool WRITE_H>
__device__ __forceinline__ void run_pass(const char* __restrict__ cur,
                                         char* __restrict__ nxt,
                                         const char* __restrict__ wbase, // uniform
                                         const float* __restrict__ colsc, // LDS
                                         f32x4* __restrict__ cacc,
                                         const int wave, const int lane) {
    const int c  = lane & 15;
    const int kq = lane >> 4;
    const int lane16 = lane * 16;
    const int j  = wave * 2 + JI;
    const int jj = __builtin_amdgcn_readfirstlane(j);   // SGPR

    v4i acc[4][4];                        // [row-tile][gate] i32
    if (!FIRST) {
#pragma unroll
        for (int rt = 0; rt < 4; rt++)
#pragma unroll
            for (int g = 0; g < 4; g++) {
                v4i z = {0, 0, 0, 0};
                acc[rt][g] = z;
            }
        const char* __restrict__ w0 = wbase + (size_t)jj * 32768; // SGPR base
        const char* __restrict__ ac = cur + lane16;
#pragma unroll 1                              // REAL loop (anti-spill)
        for (int ks = 0; ks < 8; ks++) {
            v4i B0 = *(const v4i*)(w0 + lane16 + 0);
            v4i B1 = *(const v4i*)(w0 + lane16 + 1024);
            v4i B2 = *(const v4i*)(w0 + lane16 + 2048);
            v4i B3 = *(const v4i*)(w0 + lane16 + 3072);
            __builtin_amdgcn_s_setprio(1);        // T5: MFMA cluster priority
#pragma unroll
            for (int rt = 0; rt < 4; rt++) {
                v4i A = *(const v4i*)(ac + rt * 1024);
                acc[rt][0] = __builtin_amdgcn_mfma_i32_16x16x64_i8(A, B0, acc[rt][0], 0, 0, 0);
                acc[rt][1] = __builtin_amdgcn_mfma_i32_16x16x64_i8(A, B1, acc[rt][1], 0, 0, 0);
                acc[rt][2] = __builtin_amdgcn_mfma_i32_16x16x64_i8(A, B2, acc[rt][2], 0, 0, 0);
                acc[rt][3] = __builtin_amdgcn_mfma_i32_16x16x64_i8(A, B3, acc[rt][3], 0, 0, 0);
            }
            __builtin_amdgcn_s_setprio(0);
            w0 += 4096;                   // s_add (uniform)
            ac += 4096;                   // v_add (LDS addr)
        }
    }

    // dequant: per-column combined scale from LDS (short-lived regs)
    f32x4 af[4][4];                       // [row-tile][gate] f32
    if (!FIRST) {
        const float s0 = colsc[0 * 512 + jj * 16 + c];
        const float s1 = colsc[1 * 512 + jj * 16 + c];
        const float s2 = colsc[2 * 512 + jj * 16 + c];
        const float s3 = colsc[3 * 512 + jj * 16 + c];
#pragma unroll
        for (int rt = 0; rt < 4; rt++)
#pragma unroll
            for (int r = 0; r < 4; r++) {
                af[rt][0][r] = (float)acc[rt][0][r] * s0;
                af[rt][1][r] = (float)acc[rt][1][r] * s1;
                af[rt][2][r] = (float)acc[rt][2][r] * s2;
                af[rt][3][r] = (float)acc[rt][3][r] * s3;
            }
    } else {
#pragma unroll
        for (int rt = 0; rt < 4; rt++)
#pragma unroll
            for (int g = 0; g < 4; g++) {
                f32x4 z = {0.f, 0.f, 0.f, 0.f};
                af[rt][g] = z;
            }
    }

    // f16 x/bias slice (pre-scaled by log2e / 2log2e)
    {
        const char* __restrict__ wx = wbase + WT_F16X + (size_t)jj * 4096;
        f16x8 X0 = *(const f16x8*)(wx + lane16 + 0);
        f16x8 X1 = *(const f16x8*)(wx + lane16 + 1024);
        f16x8 X2 = *(const f16x8*)(wx + lane16 + 2048);
        f16x8 X3 = *(const f16x8*)(wx + lane16 + 3072);
        const char* __restrict__ ax = cur + 32768 + lane16;
#pragma unroll
        for (int rt = 0; rt < 4; rt++) {
            f16x8 A = *(const f16x8*)(ax + rt * 1024);
            af[rt][0] = __builtin_amdgcn_mfma_f32_16x16x32_f16(A, X0, af[rt][0], 0, 0, 0);
            af[rt][1] = __builtin_amdgcn_mfma_f32_16x16x32_f16(A, X1, af[rt][1], 0, 0, 0);
            af[rt][2] = __builtin_amdgcn_mfma_f32_16x16x32_f16(A, X2, af[rt][2], 0, 0, 0);
            af[rt][3] = __builtin_amdgcn_mfma_f32_16x16x32_f16(A, X3, af[rt][3], 0, 0, 0);
        }
    }

    // epilogue: gates exp2-ready. C/D: col = lane&15, row = kq*4 + r.
#pragma unroll
    for (int rt = 0; rt < 4; rt++) {
        f32x4 cv = cacc[JI * 4 + rt];     // static index
#pragma unroll
        for (int r = 0; r < 4; r++) {
            float ai  = af[rt][0][r];         // i * log2e
            float afv = af[rt][1][r];         // f * log2e
            float ag  = af[rt][2][r];         // 2g * log2e
            float ao  = af[rt][3][r];         // o * log2e
            float ei = __builtin_amdgcn_exp2f(-ai);
            float eg = __builtin_amdgcn_exp2f(ag);
            // sig(i)*tanh(g) = (eg-1) / ((1+ei)*(1+eg))
            float ig = (eg - 1.0f) *
                       __builtin_amdgcn_rcpf((1.0f + ei) * (1.0f + eg));
            float ef = __builtin_amdgcn_exp2f(-afv);
            float cn = __builtin_amdgcn_rcpf(1.0f + ef) * cv[r] + ig;
            cv[r] = cn;
            if (WRITE_H) {
                float eo = __builtin_amdgcn_exp2f(-ao);
                float ec = __builtin_amdgcn_exp2f(cn * L2E2);
                float hn = (ec - 1.0f) *
                           __builtin_amdgcn_rcpf((1.0f + eo) * (1.0f + ec));
                // h -> i8 into next buffer's A-frag layout
                int q = (int)rintf(hn * 127.0f);
                nxt[(((j >> 2) * 4 + rt) * 64 + (kq * 4 + r) + 16 * (j & 3)) * 16 + c]
                    = (char)q;
            }
        }
        cacc[JI * 4 + rt] = cv;           // static index
    }
}

// STAGGER: even waves pass<0> then pass<1>; odd waves pass<1> then pass<0>.
// Wave-uniform branch; all register-array indices compile-time.
template <bool FIRST, bool WRITE_H>
__device__ __forceinline__ void run_step(const char* __restrict__ cur,
                                         char* __restrict__ nxt,
                                         const char* __restrict__ wbase,
                                         const float* __restrict__ colsc,
                                         f32x4* __restrict__ cacc,
                                         const int wave, const int lane) {
    if (wave & 1) {
        run_pass<FIRST, 1, WRITE_H>(cur, nxt, wbase, colsc, cacc, wave, lane);
        run_pass<FIRST, 0, WRITE_H>(cur, nxt, wbase, colsc, cacc, wave, lane);
    } else {
        run_pass<FIRST, 0, WRITE_H>(cur, nxt, wbase, colsc, cacc, wave, lane);
        run_pass<FIRST, 1, WRITE_H>(cur, nxt, wbase, colsc, cacc, wave, lane);
    }
}

// x_t (11 elems) into the f16 x-frag region of a buffer.
__device__ __forceinline__ void xfill(_Float16* __restrict__ nxt,
                                      const _Float16* __restrict__ xlds,
                                      int step, int tid) {
    for (int i = tid; i < 64 * 11; i += NTHR) {
        int row = i / 11, xi = i - row * 11;
        int idx = ((32 + (row >> 4)) * 64 + ((row & 15) + 16 * (xi >> 3))) * 8
                  + (xi & 7);
        nxt[idx] = xlds[row * 56 + step * 11 + xi];
    }
}

// ---------------- main persistent kernel ------------------------------------
__global__ __launch_bounds__(NTHR, 4)
void lstm_main(const float* __restrict__ ts,
               const char* __restrict__ Wt,
               float* __restrict__ out) {
    extern __shared__ _Float16 smem[];
    _Float16* buf0h = smem;            // h buffers (i8 region + f16 x frag)
    _Float16* buf1h = smem + HB;
    _Float16* xlds  = smem + 2 * HB;   // [64][56] fp16 staged ts rows
    float*    cslds = (float*)(smem + 2 * HB + 64 * 56);  // 2048 col scales
    char* buf0 = (char*)buf0h;
    char* buf1 = (char*)buf1h;
    const int tid  = threadIdx.x;
    const int lane = tid & 63;
    const int wave = tid >> 6;         // 0..15
    const int b0   = blockIdx.x * ROWS;
    const char* wbase = Wt;

    // zero both h buffers (covers i8 h region + f16 pad columns)
    {
        f16x8 z = {(_Float16)0, (_Float16)0, (_Float16)0, (_Float16)0,
                   (_Float16)0, (_Float16)0, (_Float16)0, (_Float16)0};
        for (int i = tid * 8; i < 2 * HB; i += NTHR * 8)
            *(f16x8*)(smem + i) = z;
    }
    // stage this block's time_series rows (coalesced) as fp16
    for (int i = tid; i < 64 * 55; i += NTHR) {
        int row = i / 55, e = i - row * 55;
        xlds[row * 56 + e] = (_Float16)ts[(size_t)(b0 + row) * 55 + e];
    }
    // stage col scales into LDS
    for (int i = tid; i < 2048; i += NTHR)
        cslds[i] = ((const float*)(Wt + WT_CSC))[i];
    __syncthreads();
    // bias column (k'=11 -> chunk 1, byte 3) = 1.0 in both buffers; x_0 -> buf0
    if (tid < 128) {
        int bsel = tid >> 6, row = tid & 63;
        int idx = ((32 + (row >> 4)) * 64 + ((row & 15) + 16)) * 8 + 3;
        (bsel ? buf1h : buf0h)[idx] = (_Float16)1.0f;
    }
    xfill(buf0h, xlds, 0, tid);
    __syncthreads();

    f32x4 cacc[8];
#pragma unroll
    for (int i = 0; i < 8; i++) {
        f32x4 z = {0.f, 0.f, 0.f, 0.f};
        cacc[i] = z;
    }

    // t = 0: h == 0, only the x/bias slice contributes
    run_step<true, true>(buf0, buf1, wbase, cslds, cacc, wave, lane);
    xfill(buf1h, xlds, 1, tid);
    __syncthreads();

    for (int t = 1; t < 4; t++) {
        char* cur = (t & 1) ? buf1 : buf0;
        char* nxt = (t & 1) ? buf0 : buf1;
        run_step<false, true>(cur, nxt, wbase, cslds, cacc, wave, lane);
        xfill((t & 1) ? (_Float16*)buf0 : (_Float16*)buf1, xlds, t + 1, tid);
        __syncthreads();
    }
    // t = 4: no h write needed
    run_step<false, false>(buf0, buf1, wbase, cslds, cacc, wave, lane);

    // write final c
    const int c = lane & 15, kq = lane >> 4;
#pragma unroll
    for (int ji = 0; ji < 2; ji++) {
        const int j = wave * 2 + ji;
#pragma unroll
        for (int rt = 0; rt < 4; rt++) {
            f32x4 cv = cacc[ji * 4 + rt];
#pragma unroll
            for (int r = 0; r < 4; r++)
                out[(size_t)(b0 + rt * 16 + kq * 4 + r) * HID + j * 16 + c] = cv[r];
        }
    }
}

extern "C" void kernel_launch(void* const* d_in, const int* in_sizes, int n_in,
                              void* d_out, int out_size, void* d_ws, size_t ws_size,
                              hipStream_t stream) {
    const float* ts  = (const float*)d_in[0];
    const float* Wih = (const float*)d_in[1];
    const float* Whh = (const float*)d_in[2];
    const float* bih = (const float*)d_in[3];
    const float* bhh = (const float*)d_in[4];
    float* out       = (float*)d_out;
    char* Wt         = (char*)d_ws;     // 1.13 MB packed weights + scales

    (void)in_sizes; (void)n_in; (void)out_size; (void)ws_size;

    hipFuncSetAttribute(reinterpret_cast<const void*>(lstm_main),
                        hipFuncAttributeMaxDynamicSharedMemorySize, SMEM_BYTES);

    pack_w<<<512, 256, 0, stream>>>(Wih, Whh, bih, bhh, Wt);
    lstm_main<<<256, NTHR, SMEM_BYTES, stream>>>(ts, Wt, out);
}